// Round 4
// baseline (7411.794 us; speedup 1.0000x reference)
//
#include <hip/hip_runtime.h>

#define H      51
#define T_IN   512
#define T_TOT  576               // 512 + 64 future
#define PITCH  52                // fp32 LDS row pitch (13 float4)
#define MROW   204
#define MSZ    (MROW * PITCH)    // 10,608 floats per matrix
#define GOFF   (3 * MSZ)         // gate buffers after 3 matrices
#define GBUFSZ (4 * 64 * 4)      // [elem][lane][gate] floats = 1024
#define LDSFL  (GOFF + 3 * GBUFSZ)   // 34,896 floats = 139,584 B

__device__ __forceinline__ float bf2f(unsigned short u) {
    return __uint_as_float(((unsigned int)u) << 16);
}
__device__ __forceinline__ unsigned short f2bf(float f) {
    unsigned int u = __float_as_uint(f);
    u += 0x7fffu + ((u >> 16) & 1u);
    return (unsigned short)(u >> 16);
}
__device__ __forceinline__ float wget(const void* p, int i, bool is16) {
    return is16 ? bf2f(((const unsigned short*)p)[i]) : ((const float*)p)[i];
}
__device__ __forceinline__ float rl(float v, int k) {
    return __uint_as_float((unsigned int)__builtin_amdgcn_readlane((int)__float_as_uint(v), k));
}
__device__ __forceinline__ float sigm(float x) {
    x = fminf(fmaxf(x, -30.f), 30.f);
    return 1.f / (1.f + __expf(-x));
}
__device__ __forceinline__ float tanh_f(float x) {
    x = fminf(fmaxf(x, -15.f), 15.f);
    float e = __expf(2.f * x);
    return (e - 1.f) / (e + 1.f);
}
__device__ __forceinline__ float f4e(float4 v, int i) {
    return i == 0 ? v.x : i == 1 ? v.y : i == 2 ? v.z : v.w;
}
__device__ __forceinline__ float4 wld4(const void* p, int row, int kb, bool is16) {
    float4 r;
    int c0 = 4 * kb;
    r.x = (c0 + 0 < H) ? wget(p, row * H + c0 + 0, is16) : 0.f;
    r.y = (c0 + 1 < H) ? wget(p, row * H + c0 + 1, is16) : 0.f;
    r.z = (c0 + 2 < H) ? wget(p, row * H + c0 + 2, is16) : 0.f;
    r.w = (c0 + 3 < H) ? wget(p, row * H + c0 + 3, is16) : 0.f;
    return r;
}

#define L13(M) M(0) M(1) M(2) M(3) M(4) M(5) M(6) M(7) M(8) M(9) M(10) M(11) M(12)

// One matvec "pass": weight element (shared across 4 batch elements) times
// broadcast h_e[k], accumulated into aa0..aa3 (element accumulators).
#define PASS_K(u, i, kb) { float wv = f4e(u, (i)); \
    aa0 = fmaf(wv, rl(HH0, 4 * (kb) + (i)), aa0); \
    aa1 = fmaf(wv, rl(HH1, 4 * (kb) + (i)), aa1); \
    aa2 = fmaf(wv, rl(HH2, 4 * (kb) + (i)), aa2); \
    aa3 = fmaf(wv, rl(HH3, 4 * (kb) + (i)), aa3); }
#define PASS_KB(kb) { float4 u = WSRC(kb); \
    PASS_K(u, 0, kb) PASS_K(u, 1, kb) PASS_K(u, 2, kb) PASS_K(u, 3, kb) }

#define UPD(q, cv, hv) { \
    float ig = sigm(q.x), fg = sigm(q.y), gg = tanh_f(q.z), og = sigm(q.w); \
    cv = fg * cv + ig * gg; hv = og * tanh_f(cv); }

#define RED(sv) { sv += __shfl_xor(sv, 32, 64); sv += __shfl_xor(sv, 16, 64); \
    sv += __shfl_xor(sv, 8, 64); sv += __shfl_xor(sv, 4, 64); \
    sv += __shfl_xor(sv, 2, 64); sv += __shfl_xor(sv, 1, 64); }

// Block = 4 waves = 4 batch elements. Wave g owns GATE g (rows g*51+j) of all
// matrices; weights read once/step, reused for 4 elements. Gate exchange via
// LDS + 1 barrier per layer (3 buffers make write-after-read safe); c/h updates
// replicated in every wave (identical deterministic fp) so h never round-trips.
extern "C" __global__ void __launch_bounds__(256, 1)
lstm3_kernel(const void* g_in,  const void* g_Wih1, const void* g_Whh1,
             const void* g_bih1, const void* g_bhh1,
             const void* g_Wih2, const void* g_Whh2, const void* g_bih2, const void* g_bhh2,
             const void* g_Wih3, const void* g_Whh3, const void* g_bih3, const void* g_bhh3,
             const void* g_Wlin, const void* g_blin, void* g_out)
{
    extern __shared__ float smem[];

    const int tid  = threadIdx.x;
    const int lane = tid & 63;
    const int wid  = tid >> 6;               // = gate index (i,f,g,o)
    const int eb   = blockIdx.x * 4;         // base batch element
    const int jeff = (lane < H) ? lane : (H - 1);
    const int row  = wid * H + jeff;         // my weight row in every matrix

    // ---- dtype sniff (proven: resolves fp32 on this harness)
    bool is16 = true;
    {
        const unsigned short* p = (const unsigned short*)g_Wih1;
        for (int i = 0; i < 204; ++i) {
            float v = fabsf(bf2f(p[i]));
            if (!(v < 0.2f)) is16 = false;
        }
    }

    // ---- LDS staging: Whh1 | Wih2 | Wih3, 204 x PITCH fp32 each
    for (int i = tid; i < GOFF; i += 256) {
        int r = i / PITCH, k = i - r * PITCH;
        const void* src; int srow;
        if (r < 204)      { src = g_Whh1; srow = r; }
        else if (r < 408) { src = g_Wih2; srow = r - 204; }
        else              { src = g_Wih3; srow = r - 408; }
        smem[i] = (k < H) ? wget(src, srow * H + k, is16) : 0.f;
    }
    __syncthreads();

    // ---- per-lane register weights: my row of Whh2 and Whh3 (no AGPR, no asm)
#define DW2(kb) float4 w2_##kb = wld4(g_Whh2, row, kb, is16);
    L13(DW2)
#define DW3(kb) float4 w3_##kb = wld4(g_Whh3, row, kb, is16);
    L13(DW3)

    const float b1r  = wget(g_bih1, row, is16) + wget(g_bhh1, row, is16);
    const float b2r  = wget(g_bih2, row, is16) + wget(g_bhh2, row, is16);
    const float b3r  = wget(g_bih3, row, is16) + wget(g_bhh3, row, is16);
    const float wi1r = wget(g_Wih1, row, is16);
    const float wlinr = (lane < H) ? wget(g_Wlin, lane, is16) : 0.f;
    const float blinr = wget(g_blin, 0, is16);

    const float4* A1 = (const float4*)(smem +          row * PITCH);   // Whh1 row
    const float4* A2 = (const float4*)(smem + MSZ +    row * PITCH);   // Wih2 row
    const float4* A3 = (const float4*)(smem + 2*MSZ +  row * PITCH);   // Wih3 row
    float* gb0 = smem + GOFF;                 // layer-1 gate buf [e][lane][gate]
    float* gb1 = smem + GOFF + GBUFSZ;
    float* gb2 = smem + GOFF + 2 * GBUFSZ;

    // replicated state: lane j holds unit j of h/c for all 4 elements
    float h1_0 = 0.f, h1_1 = 0.f, h1_2 = 0.f, h1_3 = 0.f;
    float h2_0 = 0.f, h2_1 = 0.f, h2_2 = 0.f, h2_3 = 0.f;
    float h3_0 = 0.f, h3_1 = 0.f, h3_2 = 0.f, h3_3 = 0.f;
    float c1_0 = 0.f, c1_1 = 0.f, c1_2 = 0.f, c1_3 = 0.f;
    float c2_0 = 0.f, c2_1 = 0.f, c2_2 = 0.f, c2_3 = 0.f;
    float c3_0 = 0.f, c3_1 = 0.f, c3_2 = 0.f, c3_3 = 0.f;
    float xf0 = 0.f, xf1 = 0.f, xf2 = 0.f, xf3 = 0.f;

    const unsigned short* in16 = (const unsigned short*)g_in;
    const float*          in32 = (const float*)g_in;
    unsigned short* o16w = (unsigned short*)g_out + (size_t)(eb + wid) * T_TOT;
    float*          o32w = (float*)g_out          + (size_t)(eb + wid) * T_TOT;

#pragma clang loop unroll(disable)
    for (int t = 0; t < T_TOT; ++t) {
        float x0, x1, x2, x3;
        if (t < T_IN) {
            if (is16) {
                x0 = bf2f(in16[(size_t)(eb + 0) * T_IN + t]);
                x1 = bf2f(in16[(size_t)(eb + 1) * T_IN + t]);
                x2 = bf2f(in16[(size_t)(eb + 2) * T_IN + t]);
                x3 = bf2f(in16[(size_t)(eb + 3) * T_IN + t]);
            } else {
                x0 = in32[(size_t)(eb + 0) * T_IN + t];
                x1 = in32[(size_t)(eb + 1) * T_IN + t];
                x2 = in32[(size_t)(eb + 2) * T_IN + t];
                x3 = in32[(size_t)(eb + 3) * T_IN + t];
            }
        } else { x0 = xf0; x1 = xf1; x2 = xf2; x3 = xf3; }

        float aa0, aa1, aa2, aa3;

        // ================= layer 1: b1 + Wih1*x + Whh1 . h1(old) =================
        aa0 = fmaf(wi1r, x0, b1r);
        aa1 = fmaf(wi1r, x1, b1r);
        aa2 = fmaf(wi1r, x2, b1r);
        aa3 = fmaf(wi1r, x3, b1r);
#define WSRC(kb) A1[kb]
#define HH0 h1_0
#define HH1 h1_1
#define HH2 h1_2
#define HH3 h1_3
        L13(PASS_KB)
#undef WSRC
#undef HH0
#undef HH1
#undef HH2
#undef HH3
        if (lane < H) {
            gb0[(0 * 64 + lane) * 4 + wid] = aa0;
            gb0[(1 * 64 + lane) * 4 + wid] = aa1;
            gb0[(2 * 64 + lane) * 4 + wid] = aa2;
            gb0[(3 * 64 + lane) * 4 + wid] = aa3;
        }
        __syncthreads();
        {
            float4 q0 = *(const float4*)(gb0 + (0 * 64 + jeff) * 4);
            float4 q1 = *(const float4*)(gb0 + (1 * 64 + jeff) * 4);
            float4 q2 = *(const float4*)(gb0 + (2 * 64 + jeff) * 4);
            float4 q3 = *(const float4*)(gb0 + (3 * 64 + jeff) * 4);
            UPD(q0, c1_0, h1_0) UPD(q1, c1_1, h1_1)
            UPD(q2, c1_2, h1_2) UPD(q3, c1_3, h1_3)
        }

        // ============ layer 2: b2 + Wih2 . h1(new) + Whh2 . h2(old) ============
        aa0 = b2r; aa1 = b2r; aa2 = b2r; aa3 = b2r;
#define WSRC(kb) A2[kb]
#define HH0 h1_0
#define HH1 h1_1
#define HH2 h1_2
#define HH3 h1_3
        L13(PASS_KB)
#undef WSRC
#undef HH0
#undef HH1
#undef HH2
#undef HH3
#define WSRC(kb) w2_##kb
#define HH0 h2_0
#define HH1 h2_1
#define HH2 h2_2
#define HH3 h2_3
        L13(PASS_KB)
#undef WSRC
#undef HH0
#undef HH1
#undef HH2
#undef HH3
        if (lane < H) {
            gb1[(0 * 64 + lane) * 4 + wid] = aa0;
            gb1[(1 * 64 + lane) * 4 + wid] = aa1;
            gb1[(2 * 64 + lane) * 4 + wid] = aa2;
            gb1[(3 * 64 + lane) * 4 + wid] = aa3;
        }
        __syncthreads();
        {
            float4 q0 = *(const float4*)(gb1 + (0 * 64 + jeff) * 4);
            float4 q1 = *(const float4*)(gb1 + (1 * 64 + jeff) * 4);
            float4 q2 = *(const float4*)(gb1 + (2 * 64 + jeff) * 4);
            float4 q3 = *(const float4*)(gb1 + (3 * 64 + jeff) * 4);
            UPD(q0, c2_0, h2_0) UPD(q1, c2_1, h2_1)
            UPD(q2, c2_2, h2_2) UPD(q3, c2_3, h2_3)
        }

        // ============ layer 3: b3 + Wih3 . h2(new) + Whh3 . h3(old) ============
        aa0 = b3r; aa1 = b3r; aa2 = b3r; aa3 = b3r;
#define WSRC(kb) A3[kb]
#define HH0 h2_0
#define HH1 h2_1
#define HH2 h2_2
#define HH3 h2_3
        L13(PASS_KB)
#undef WSRC
#undef HH0
#undef HH1
#undef HH2
#undef HH3
#define WSRC(kb) w3_##kb
#define HH0 h3_0
#define HH1 h3_1
#define HH2 h3_2
#define HH3 h3_3
        L13(PASS_KB)
#undef WSRC
#undef HH0
#undef HH1
#undef HH2
#undef HH3
        if (lane < H) {
            gb2[(0 * 64 + lane) * 4 + wid] = aa0;
            gb2[(1 * 64 + lane) * 4 + wid] = aa1;
            gb2[(2 * 64 + lane) * 4 + wid] = aa2;
            gb2[(3 * 64 + lane) * 4 + wid] = aa3;
        }
        __syncthreads();
        {
            float4 q0 = *(const float4*)(gb2 + (0 * 64 + jeff) * 4);
            float4 q1 = *(const float4*)(gb2 + (1 * 64 + jeff) * 4);
            float4 q2 = *(const float4*)(gb2 + (2 * 64 + jeff) * 4);
            float4 q3 = *(const float4*)(gb2 + (3 * 64 + jeff) * 4);
            UPD(q0, c3_0, h3_0) UPD(q1, c3_1, h3_1)
            UPD(q2, c3_2, h3_2) UPD(q3, c3_3, h3_3)
        }

        // ======== linear head (replicated per wave -> identical feedback) ========
        float s0 = wlinr * h3_0; RED(s0) float ov0 = s0 + blinr;
        float s1 = wlinr * h3_1; RED(s1) float ov1 = s1 + blinr;
        float s2 = wlinr * h3_2; RED(s2) float ov2 = s2 + blinr;
        float s3 = wlinr * h3_3; RED(s3) float ov3 = s3 + blinr;
        xf0 = ov0; xf1 = ov1; xf2 = ov2; xf3 = ov3;

        float myov = (wid == 0) ? ov0 : (wid == 1) ? ov1 : (wid == 2) ? ov2 : ov3;
        if (lane == 0) {
            if (is16) o16w[t] = f2bf(myov);
            else      o32w[t] = myov;
        }
    }
}

extern "C" void kernel_launch(void* const* d_in, const int* in_sizes, int n_in,
                              void* d_out, int out_size, void* d_ws, size_t ws_size,
                              hipStream_t stream) {
    (void)in_sizes; (void)n_in; (void)d_ws; (void)ws_size; (void)out_size;
    size_t shmem = LDSFL * sizeof(float);   // 139,584 B
    hipFuncSetAttribute((const void*)lstm3_kernel,
                        hipFuncAttributeMaxDynamicSharedMemorySize, (int)shmem);
    lstm3_kernel<<<dim3(256), dim3(256), shmem, stream>>>(
        d_in[0],  d_in[1],  d_in[2],  d_in[3],  d_in[4],
        d_in[5],  d_in[6],  d_in[7],  d_in[8],
        d_in[9],  d_in[10], d_in[11], d_in[12],
        d_in[13], d_in[14], d_out);
}

// Round 5
// 3436.662 us; speedup vs baseline: 2.1567x; 2.1567x over previous
//
#include <hip/hip_runtime.h>

#define H      51
#define T_IN   512
#define T_TOT  576                 // 512 + 64 future
#define EBF4   (3 * 4 * 4 * 64)    // exchange float4s: [layer][elem][wave][lane]
#define LDSBYTES (EBF4 * 16)       // 49,152 B

__device__ __forceinline__ float bf2f(unsigned short u) {
    return __uint_as_float(((unsigned int)u) << 16);
}
__device__ __forceinline__ unsigned short f2bf(float f) {
    unsigned int u = __float_as_uint(f);
    u += 0x7fffu + ((u >> 16) & 1u);
    return (unsigned short)(u >> 16);
}
__device__ __forceinline__ float wget(const void* p, int i, bool is16) {
    return is16 ? bf2f(((const unsigned short*)p)[i]) : ((const float*)p)[i];
}
__device__ __forceinline__ float rl(float v, int k) {
    return __uint_as_float((unsigned int)__builtin_amdgcn_readlane((int)__float_as_uint(v), k));
}
__device__ __forceinline__ float sigm(float x) {
    x = fminf(fmaxf(x, -30.f), 30.f);
    return 1.f / (1.f + __expf(-x));
}
__device__ __forceinline__ float tanh_f(float x) {
    x = fminf(fmaxf(x, -15.f), 15.f);
    float e = __expf(2.f * x);
    return (e - 1.f) / (e + 1.f);
}

#define L13(M) M(0) M(1) M(2) M(3) M(4) M(5) M(6) M(7) M(8) M(9) M(10) M(11) M(12)

#define UPD(q, cv, hv) { \
    float ig = sigm(q.x), fg = sigm(q.y), gg = tanh_f(q.z), og = sigm(q.w); \
    cv = fg * cv + ig * gg; hv = og * tanh_f(cv); }

#define RED(sv) { sv += __shfl_xor(sv, 32, 64); sv += __shfl_xor(sv, 16, 64); \
    sv += __shfl_xor(sv, 8, 64); sv += __shfl_xor(sv, 4, 64); \
    sv += __shfl_xor(sv, 2, 64); sv += __shfl_xor(sv, 1, 64); }

// K-split persistent LSTM: block = 4 waves = 4 batch elements. Wave w owns
// k-slice [13w,13w+13) of ALL gates/matrices; all 260 weights/lane live in
// registers (104 VGPR + 156 AGPR via v_accvgpr asm) -> zero LDS weight reads
// in the time loop. Per layer: 16 partial sums exchanged via LDS (1 barrier),
// then UPD replicated in every wave (identical fp => identical h everywhere).
extern "C" __global__ void __launch_bounds__(256, 1)
lstm3_kernel(const void* g_in,  const void* g_Wih1, const void* g_Whh1,
             const void* g_bih1, const void* g_bhh1,
             const void* g_Wih2, const void* g_Whh2, const void* g_bih2, const void* g_bhh2,
             const void* g_Wih3, const void* g_Whh3, const void* g_bih3, const void* g_bhh3,
             const void* g_Wlin, const void* g_blin, void* g_out)
{
    extern __shared__ float4 ebuf4[];   // [3][4 elem][4 wave][64 lane]

    const int tid  = threadIdx.x;
    const int lane = tid & 63;
    const int wid  = tid >> 6;               // k-slice owner
    const int eb   = blockIdx.x * 4;
    const int jeff = (lane < H) ? lane : (H - 1);
    const int kb13 = 13 * wid;               // my k-slice base

    // ---- dtype sniff (proven: resolves fp32 on this harness)
    bool is16 = true;
    {
        const unsigned short* p = (const unsigned short*)g_Wih1;
        for (int i = 0; i < 204; ++i) {
            float v = fabsf(bf2f(p[i]));
            if (!(v < 0.2f)) is16 = false;
        }
    }

#define WC(srcp, row, kk) (((kb13 + (kk)) < H) ? wget(srcp, (row) * H + kb13 + (kk), is16) : 0.f)

#define DECL13(p) float p##_0,p##_1,p##_2,p##_3,p##_4,p##_5,p##_6,p##_7,p##_8,p##_9,p##_10,p##_11,p##_12;
#define LOAD13(p, srcp, row) \
    p##_0 = WC(srcp, row, 0);  p##_1 = WC(srcp, row, 1);  p##_2 = WC(srcp, row, 2); \
    p##_3 = WC(srcp, row, 3);  p##_4 = WC(srcp, row, 4);  p##_5 = WC(srcp, row, 5); \
    p##_6 = WC(srcp, row, 6);  p##_7 = WC(srcp, row, 7);  p##_8 = WC(srcp, row, 8); \
    p##_9 = WC(srcp, row, 9);  p##_10 = WC(srcp, row, 10); p##_11 = WC(srcp, row, 11); \
    p##_12 = WC(srcp, row, 12);
#define AGW1(p, kk, srcp, row) { float t_ = WC(srcp, row, kk); \
    asm volatile("v_accvgpr_write_b32 %0, %1" : "=a"(p##_##kk) : "v"(t_)); }
#define AGLOAD13(p, srcp, row) \
    AGW1(p,0,srcp,row)  AGW1(p,1,srcp,row)  AGW1(p,2,srcp,row)  AGW1(p,3,srcp,row) \
    AGW1(p,4,srcp,row)  AGW1(p,5,srcp,row)  AGW1(p,6,srcp,row)  AGW1(p,7,srcp,row) \
    AGW1(p,8,srcp,row)  AGW1(p,9,srcp,row)  AGW1(p,10,srcp,row) AGW1(p,11,srcp,row) \
    AGW1(p,12,srcp,row)
#define AGR(p, kk, d) asm volatile("v_accvgpr_read_b32 %0, %1" : "=v"(d) : "a"(p##_##kk));

    // ---- VGPR weights: Wih2, Whh2 (8 sets x 13 = 104 regs)
    DECL13(wih2g0) DECL13(wih2g1) DECL13(wih2g2) DECL13(wih2g3)
    DECL13(whh2g0) DECL13(whh2g1) DECL13(whh2g2) DECL13(whh2g3)
    LOAD13(wih2g0, g_Wih2, 0 * H + jeff) LOAD13(wih2g1, g_Wih2, 1 * H + jeff)
    LOAD13(wih2g2, g_Wih2, 2 * H + jeff) LOAD13(wih2g3, g_Wih2, 3 * H + jeff)
    LOAD13(whh2g0, g_Whh2, 0 * H + jeff) LOAD13(whh2g1, g_Whh2, 1 * H + jeff)
    LOAD13(whh2g2, g_Whh2, 2 * H + jeff) LOAD13(whh2g3, g_Whh2, 3 * H + jeff)

    // ---- AGPR weights: Whh1, Wih3, Whh3 (12 sets x 13 = 156 AGPRs)
    DECL13(whh1g0) DECL13(whh1g1) DECL13(whh1g2) DECL13(whh1g3)
    DECL13(wih3g0) DECL13(wih3g1) DECL13(wih3g2) DECL13(wih3g3)
    DECL13(whh3g0) DECL13(whh3g1) DECL13(whh3g2) DECL13(whh3g3)
    AGLOAD13(whh1g0, g_Whh1, 0 * H + jeff) AGLOAD13(whh1g1, g_Whh1, 1 * H + jeff)
    AGLOAD13(whh1g2, g_Whh1, 2 * H + jeff) AGLOAD13(whh1g3, g_Whh1, 3 * H + jeff)
    AGLOAD13(wih3g0, g_Wih3, 0 * H + jeff) AGLOAD13(wih3g1, g_Wih3, 1 * H + jeff)
    AGLOAD13(wih3g2, g_Wih3, 2 * H + jeff) AGLOAD13(wih3g3, g_Wih3, 3 * H + jeff)
    AGLOAD13(whh3g0, g_Whh3, 0 * H + jeff) AGLOAD13(whh3g1, g_Whh3, 1 * H + jeff)
    AGLOAD13(whh3g2, g_Whh3, 2 * H + jeff) AGLOAD13(whh3g3, g_Whh3, 3 * H + jeff)

    // ---- biases (added only by wave 0's partials), input weight, head
    const float b1_0 = wget(g_bih1, 0*H+jeff, is16) + wget(g_bhh1, 0*H+jeff, is16);
    const float b1_1 = wget(g_bih1, 1*H+jeff, is16) + wget(g_bhh1, 1*H+jeff, is16);
    const float b1_2 = wget(g_bih1, 2*H+jeff, is16) + wget(g_bhh1, 2*H+jeff, is16);
    const float b1_3 = wget(g_bih1, 3*H+jeff, is16) + wget(g_bhh1, 3*H+jeff, is16);
    const float b2_0 = wget(g_bih2, 0*H+jeff, is16) + wget(g_bhh2, 0*H+jeff, is16);
    const float b2_1 = wget(g_bih2, 1*H+jeff, is16) + wget(g_bhh2, 1*H+jeff, is16);
    const float b2_2 = wget(g_bih2, 2*H+jeff, is16) + wget(g_bhh2, 2*H+jeff, is16);
    const float b2_3 = wget(g_bih2, 3*H+jeff, is16) + wget(g_bhh2, 3*H+jeff, is16);
    const float b3_0 = wget(g_bih3, 0*H+jeff, is16) + wget(g_bhh3, 0*H+jeff, is16);
    const float b3_1 = wget(g_bih3, 1*H+jeff, is16) + wget(g_bhh3, 1*H+jeff, is16);
    const float b3_2 = wget(g_bih3, 2*H+jeff, is16) + wget(g_bhh3, 2*H+jeff, is16);
    const float b3_3 = wget(g_bih3, 3*H+jeff, is16) + wget(g_bhh3, 3*H+jeff, is16);
    const float wi1_0 = wget(g_Wih1, 0*H+jeff, is16);
    const float wi1_1 = wget(g_Wih1, 1*H+jeff, is16);
    const float wi1_2 = wget(g_Wih1, 2*H+jeff, is16);
    const float wi1_3 = wget(g_Wih1, 3*H+jeff, is16);
    const float wlinr = (lane < H) ? wget(g_Wlin, lane, is16) : 0.f;
    const float blinr = wget(g_blin, 0, is16);

    // replicated state: lane j holds unit j of h/c for all 4 elements, in every wave
    float h1_0=0.f,h1_1=0.f,h1_2=0.f,h1_3=0.f;
    float h2_0=0.f,h2_1=0.f,h2_2=0.f,h2_3=0.f;
    float h3_0=0.f,h3_1=0.f,h3_2=0.f,h3_3=0.f;
    float c1_0=0.f,c1_1=0.f,c1_2=0.f,c1_3=0.f;
    float c2_0=0.f,c2_1=0.f,c2_2=0.f,c2_3=0.f;
    float c3_0=0.f,c3_1=0.f,c3_2=0.f,c3_3=0.f;
    float xf0=0.f,xf1=0.f,xf2=0.f,xf3=0.f;

    const unsigned short* in16 = (const unsigned short*)g_in;
    const float*          in32 = (const float*)g_in;
    unsigned short* o16w = (unsigned short*)g_out + (size_t)(eb + wid) * T_TOT;
    float*          o32w = (float*)g_out          + (size_t)(eb + wid) * T_TOT;

    // ---- pass macros: per kk, broadcast h[k] once, feed 4 gates x 4 elements
#define P1(kk) { \
    float s0=rl(h1_0,kb13+kk), s1=rl(h1_1,kb13+kk), s2=rl(h1_2,kb13+kk), s3=rl(h1_3,kb13+kk); \
    float w0,w1,w2,w3; AGR(whh1g0,kk,w0) AGR(whh1g1,kk,w1) AGR(whh1g2,kk,w2) AGR(whh1g3,kk,w3) \
    a00=fmaf(w0,s0,a00); a01=fmaf(w0,s1,a01); a02=fmaf(w0,s2,a02); a03=fmaf(w0,s3,a03); \
    a10=fmaf(w1,s0,a10); a11=fmaf(w1,s1,a11); a12=fmaf(w1,s2,a12); a13=fmaf(w1,s3,a13); \
    a20=fmaf(w2,s0,a20); a21=fmaf(w2,s1,a21); a22=fmaf(w2,s2,a22); a23=fmaf(w2,s3,a23); \
    a30=fmaf(w3,s0,a30); a31=fmaf(w3,s1,a31); a32=fmaf(w3,s2,a32); a33=fmaf(w3,s3,a33); }

#define P2(kk) { \
    float s0=rl(h1_0,kb13+kk), s1=rl(h1_1,kb13+kk), s2=rl(h1_2,kb13+kk), s3=rl(h1_3,kb13+kk); \
    float r0=rl(h2_0,kb13+kk), r1=rl(h2_1,kb13+kk), r2=rl(h2_2,kb13+kk), r3=rl(h2_3,kb13+kk); \
    a00=fmaf(whh2g0_##kk,r0,fmaf(wih2g0_##kk,s0,a00)); a01=fmaf(whh2g0_##kk,r1,fmaf(wih2g0_##kk,s1,a01)); \
    a02=fmaf(whh2g0_##kk,r2,fmaf(wih2g0_##kk,s2,a02)); a03=fmaf(whh2g0_##kk,r3,fmaf(wih2g0_##kk,s3,a03)); \
    a10=fmaf(whh2g1_##kk,r0,fmaf(wih2g1_##kk,s0,a10)); a11=fmaf(whh2g1_##kk,r1,fmaf(wih2g1_##kk,s1,a11)); \
    a12=fmaf(whh2g1_##kk,r2,fmaf(wih2g1_##kk,s2,a12)); a13=fmaf(whh2g1_##kk,r3,fmaf(wih2g1_##kk,s3,a13)); \
    a20=fmaf(whh2g2_##kk,r0,fmaf(wih2g2_##kk,s0,a20)); a21=fmaf(whh2g2_##kk,r1,fmaf(wih2g2_##kk,s1,a21)); \
    a22=fmaf(whh2g2_##kk,r2,fmaf(wih2g2_##kk,s2,a22)); a23=fmaf(whh2g2_##kk,r3,fmaf(wih2g2_##kk,s3,a23)); \
    a30=fmaf(whh2g3_##kk,r0,fmaf(wih2g3_##kk,s0,a30)); a31=fmaf(whh2g3_##kk,r1,fmaf(wih2g3_##kk,s1,a31)); \
    a32=fmaf(whh2g3_##kk,r2,fmaf(wih2g3_##kk,s2,a32)); a33=fmaf(whh2g3_##kk,r3,fmaf(wih2g3_##kk,s3,a33)); }

#define P3(kk) { \
    float s0=rl(h2_0,kb13+kk), s1=rl(h2_1,kb13+kk), s2=rl(h2_2,kb13+kk), s3=rl(h2_3,kb13+kk); \
    float r0=rl(h3_0,kb13+kk), r1=rl(h3_1,kb13+kk), r2=rl(h3_2,kb13+kk), r3=rl(h3_3,kb13+kk); \
    float u0,u1,u2,u3,v0,v1,v2,v3; \
    AGR(wih3g0,kk,u0) AGR(wih3g1,kk,u1) AGR(wih3g2,kk,u2) AGR(wih3g3,kk,u3) \
    AGR(whh3g0,kk,v0) AGR(whh3g1,kk,v1) AGR(whh3g2,kk,v2) AGR(whh3g3,kk,v3) \
    a00=fmaf(v0,r0,fmaf(u0,s0,a00)); a01=fmaf(v0,r1,fmaf(u0,s1,a01)); \
    a02=fmaf(v0,r2,fmaf(u0,s2,a02)); a03=fmaf(v0,r3,fmaf(u0,s3,a03)); \
    a10=fmaf(v1,r0,fmaf(u1,s0,a10)); a11=fmaf(v1,r1,fmaf(u1,s1,a11)); \
    a12=fmaf(v1,r2,fmaf(u1,s2,a12)); a13=fmaf(v1,r3,fmaf(u1,s3,a13)); \
    a20=fmaf(v2,r0,fmaf(u2,s0,a20)); a21=fmaf(v2,r1,fmaf(u2,s1,a21)); \
    a22=fmaf(v2,r2,fmaf(u2,s2,a22)); a23=fmaf(v2,r3,fmaf(u2,s3,a23)); \
    a30=fmaf(v3,r0,fmaf(u3,s0,a30)); a31=fmaf(v3,r1,fmaf(u3,s1,a31)); \
    a32=fmaf(v3,r2,fmaf(u3,s2,a32)); a33=fmaf(v3,r3,fmaf(u3,s3,a33)); }

    // write 4 partial-float4s, barrier, reduce over 4 waves (fixed order), UPD x4
#define EXCH(Lidx, c0v,h0v, c1v,h1v, c2v,h2v, c3v,h3v) { \
    float4 p_; \
    p_.x=a00; p_.y=a10; p_.z=a20; p_.w=a30; ebuf4[(((Lidx)*4+0)*4+wid)*64+lane]=p_; \
    p_.x=a01; p_.y=a11; p_.z=a21; p_.w=a31; ebuf4[(((Lidx)*4+1)*4+wid)*64+lane]=p_; \
    p_.x=a02; p_.y=a12; p_.z=a22; p_.w=a32; ebuf4[(((Lidx)*4+2)*4+wid)*64+lane]=p_; \
    p_.x=a03; p_.y=a13; p_.z=a23; p_.w=a33; ebuf4[(((Lidx)*4+3)*4+wid)*64+lane]=p_; \
    __syncthreads(); \
    float4 q_, t_; \
    q_ = ebuf4[(((Lidx)*4+0)*4+0)*64+lane]; \
    t_ = ebuf4[(((Lidx)*4+0)*4+1)*64+lane]; q_.x+=t_.x; q_.y+=t_.y; q_.z+=t_.z; q_.w+=t_.w; \
    t_ = ebuf4[(((Lidx)*4+0)*4+2)*64+lane]; q_.x+=t_.x; q_.y+=t_.y; q_.z+=t_.z; q_.w+=t_.w; \
    t_ = ebuf4[(((Lidx)*4+0)*4+3)*64+lane]; q_.x+=t_.x; q_.y+=t_.y; q_.z+=t_.z; q_.w+=t_.w; \
    UPD(q_, c0v, h0v) \
    q_ = ebuf4[(((Lidx)*4+1)*4+0)*64+lane]; \
    t_ = ebuf4[(((Lidx)*4+1)*4+1)*64+lane]; q_.x+=t_.x; q_.y+=t_.y; q_.z+=t_.z; q_.w+=t_.w; \
    t_ = ebuf4[(((Lidx)*4+1)*4+2)*64+lane]; q_.x+=t_.x; q_.y+=t_.y; q_.z+=t_.z; q_.w+=t_.w; \
    t_ = ebuf4[(((Lidx)*4+1)*4+3)*64+lane]; q_.x+=t_.x; q_.y+=t_.y; q_.z+=t_.z; q_.w+=t_.w; \
    UPD(q_, c1v, h1v) \
    q_ = ebuf4[(((Lidx)*4+2)*4+0)*64+lane]; \
    t_ = ebuf4[(((Lidx)*4+2)*4+1)*64+lane]; q_.x+=t_.x; q_.y+=t_.y; q_.z+=t_.z; q_.w+=t_.w; \
    t_ = ebuf4[(((Lidx)*4+2)*4+2)*64+lane]; q_.x+=t_.x; q_.y+=t_.y; q_.z+=t_.z; q_.w+=t_.w; \
    t_ = ebuf4[(((Lidx)*4+2)*4+3)*64+lane]; q_.x+=t_.x; q_.y+=t_.y; q_.z+=t_.z; q_.w+=t_.w; \
    UPD(q_, c2v, h2v) \
    q_ = ebuf4[(((Lidx)*4+3)*4+0)*64+lane]; \
    t_ = ebuf4[(((Lidx)*4+3)*4+1)*64+lane]; q_.x+=t_.x; q_.y+=t_.y; q_.z+=t_.z; q_.w+=t_.w; \
    t_ = ebuf4[(((Lidx)*4+3)*4+2)*64+lane]; q_.x+=t_.x; q_.y+=t_.y; q_.z+=t_.z; q_.w+=t_.w; \
    t_ = ebuf4[(((Lidx)*4+3)*4+3)*64+lane]; q_.x+=t_.x; q_.y+=t_.y; q_.z+=t_.z; q_.w+=t_.w; \
    UPD(q_, c3v, h3v) }

#pragma clang loop unroll(disable)
    for (int t = 0; t < T_TOT; ++t) {
        float a00,a01,a02,a03,a10,a11,a12,a13,a20,a21,a22,a23,a30,a31,a32,a33;

        // ---------- layer 1: wave 0 seeds bias + Wih1*x; others seed 0 ----------
        if (wid == 0) {
            float x0, x1, x2, x3;
            if (t < T_IN) {
                if (is16) {
                    x0 = bf2f(in16[(size_t)(eb+0)*T_IN + t]);
                    x1 = bf2f(in16[(size_t)(eb+1)*T_IN + t]);
                    x2 = bf2f(in16[(size_t)(eb+2)*T_IN + t]);
                    x3 = bf2f(in16[(size_t)(eb+3)*T_IN + t]);
                } else {
                    x0 = in32[(size_t)(eb+0)*T_IN + t];
                    x1 = in32[(size_t)(eb+1)*T_IN + t];
                    x2 = in32[(size_t)(eb+2)*T_IN + t];
                    x3 = in32[(size_t)(eb+3)*T_IN + t];
                }
            } else { x0 = xf0; x1 = xf1; x2 = xf2; x3 = xf3; }
            a00=fmaf(wi1_0,x0,b1_0); a01=fmaf(wi1_0,x1,b1_0); a02=fmaf(wi1_0,x2,b1_0); a03=fmaf(wi1_0,x3,b1_0);
            a10=fmaf(wi1_1,x0,b1_1); a11=fmaf(wi1_1,x1,b1_1); a12=fmaf(wi1_1,x2,b1_1); a13=fmaf(wi1_1,x3,b1_1);
            a20=fmaf(wi1_2,x0,b1_2); a21=fmaf(wi1_2,x1,b1_2); a22=fmaf(wi1_2,x2,b1_2); a23=fmaf(wi1_2,x3,b1_2);
            a30=fmaf(wi1_3,x0,b1_3); a31=fmaf(wi1_3,x1,b1_3); a32=fmaf(wi1_3,x2,b1_3); a33=fmaf(wi1_3,x3,b1_3);
        } else {
            a00=a01=a02=a03=a10=a11=a12=a13=a20=a21=a22=a23=a30=a31=a32=a33=0.f;
        }
        L13(P1)
        EXCH(0, c1_0,h1_0, c1_1,h1_1, c1_2,h1_2, c1_3,h1_3)

        // ---------- layer 2 ----------
        if (wid == 0) {
            a00=a01=a02=a03=b2_0; a10=a11=a12=a13=b2_1;
            a20=a21=a22=a23=b2_2; a30=a31=a32=a33=b2_3;
        } else {
            a00=a01=a02=a03=a10=a11=a12=a13=a20=a21=a22=a23=a30=a31=a32=a33=0.f;
        }
        L13(P2)
        EXCH(1, c2_0,h2_0, c2_1,h2_1, c2_2,h2_2, c2_3,h2_3)

        // ---------- layer 3 ----------
        if (wid == 0) {
            a00=a01=a02=a03=b3_0; a10=a11=a12=a13=b3_1;
            a20=a21=a22=a23=b3_2; a30=a31=a32=a33=b3_3;
        } else {
            a00=a01=a02=a03=a10=a11=a12=a13=a20=a21=a22=a23=a30=a31=a32=a33=0.f;
        }
        L13(P3)
        EXCH(2, c3_0,h3_0, c3_1,h3_1, c3_2,h3_2, c3_3,h3_3)

        // -------- head (replicated -> identical feedback everywhere) --------
        float s0 = wlinr * h3_0; RED(s0) float ov0 = s0 + blinr;
        float s1 = wlinr * h3_1; RED(s1) float ov1 = s1 + blinr;
        float s2 = wlinr * h3_2; RED(s2) float ov2 = s2 + blinr;
        float s3 = wlinr * h3_3; RED(s3) float ov3 = s3 + blinr;
        xf0 = ov0; xf1 = ov1; xf2 = ov2; xf3 = ov3;

        float myov = (wid == 0) ? ov0 : (wid == 1) ? ov1 : (wid == 2) ? ov2 : ov3;
        if (lane == 0) {
            if (is16) o16w[t] = f2bf(myov);
            else      o32w[t] = myov;
        }
    }
}

extern "C" void kernel_launch(void* const* d_in, const int* in_sizes, int n_in,
                              void* d_out, int out_size, void* d_ws, size_t ws_size,
                              hipStream_t stream) {
    (void)in_sizes; (void)n_in; (void)d_ws; (void)ws_size; (void)out_size;
    lstm3_kernel<<<dim3(256), dim3(256), LDSBYTES, stream>>>(
        d_in[0],  d_in[1],  d_in[2],  d_in[3],  d_in[4],
        d_in[5],  d_in[6],  d_in[7],  d_in[8],
        d_in[9],  d_in[10], d_in[11], d_in[12],
        d_in[13], d_in[14], d_out);
}

// Round 6
// 3053.504 us; speedup vs baseline: 2.4273x; 1.1255x over previous
//
#include <hip/hip_runtime.h>

#define H      51
#define T_IN   512
#define T_TOT  576
#define PITCH  52
// float offsets within smem
#define OFF_W1 0                          // Whh1: 204 x 52
#define OFF_W3 (204 * PITCH)              // Wih3 gates f,g,o: 153 x 52
#define OFF_P  (OFF_W3 + 153 * PITCH)     // partial buf: [2 elem][4 wave][52] float4
#define OFF_H  (OFF_P + 2 * 4 * PITCH * 4)// h broadcast: [2 elem][52] float
#define LDSFL  (OFF_H + 2 * PITCH)        // 20,332 floats = 81,328 B (2 blocks/CU)

__device__ __forceinline__ float bf2f(unsigned short u) {
    return __uint_as_float(((unsigned int)u) << 16);
}
__device__ __forceinline__ unsigned short f2bf(float f) {
    unsigned int u = __float_as_uint(f);
    u += 0x7fffu + ((u >> 16) & 1u);
    return (unsigned short)(u >> 16);
}
__device__ __forceinline__ float wget(const void* p, int i, bool is16) {
    return is16 ? bf2f(((const unsigned short*)p)[i]) : ((const float*)p)[i];
}
__device__ __forceinline__ float rl(float v, int k) {
    return __uint_as_float((unsigned int)__builtin_amdgcn_readlane((int)__float_as_uint(v), k));
}
__device__ __forceinline__ float sigm(float x) {
    x = fminf(fmaxf(x, -30.f), 30.f);
    return 1.f / (1.f + __expf(-x));
}
__device__ __forceinline__ float tanh_f(float x) {
    x = fminf(fmaxf(x, -15.f), 15.f);
    float e = __expf(2.f * x);
    return (e - 1.f) / (e + 1.f);
}
__device__ __forceinline__ float f4e(float4 v, int i) {
    return i == 0 ? v.x : i == 1 ? v.y : i == 2 ? v.z : v.w;
}

#define L13(M) M(0) M(1) M(2) M(3) M(4) M(5) M(6) M(7) M(8) M(9) M(10) M(11) M(12)

#define RED(sv) { sv += __shfl_xor(sv, 32, 64); sv += __shfl_xor(sv, 16, 64); \
    sv += __shfl_xor(sv, 8, 64); sv += __shfl_xor(sv, 4, 64); \
    sv += __shfl_xor(sv, 2, 64); sv += __shfl_xor(sv, 1, 64); }

// 512 blocks x 4 waves; block = 2 batch elements. Wave w owns k-slice 13w..13w+12
// of the register matrices (Wih2, Whh2, Whh3, Wih3-gate-i: 169 regs/lane) and an
// aligned k-slice of the LDS matrices (Whh1, Wih3 f/g/o). Partials for 4 gates x
// 2 elems exchanged via one LDS buffer; waves 0/2 do the UPD for elem 0/1 and
// rebroadcast h via LDS; wave 3 does input/bias/head/store. <=256 regs/wave and
// 81,328 B LDS -> 2 independent blocks per CU (2 waves/SIMD) to hide latency.
extern "C" __global__ void __launch_bounds__(256, 2)
lstm3_kernel(const void* g_in,  const void* g_Wih1, const void* g_Whh1,
             const void* g_bih1, const void* g_bhh1,
             const void* g_Wih2, const void* g_Whh2, const void* g_bih2, const void* g_bhh2,
             const void* g_Wih3, const void* g_Whh3, const void* g_bih3, const void* g_bhh3,
             const void* g_Wlin, const void* g_blin, void* g_out)
{
    extern __shared__ float smem[];

    const int tid  = threadIdx.x;
    const int lane = tid & 63;
    const int wid  = tid >> 6;
    const int eb   = blockIdx.x * 2;
    const int jeff = (lane < H) ? lane : (H - 1);

    // ---- dtype sniff (proven: resolves fp32 on this harness)
    bool is16 = true;
    {
        const unsigned short* p = (const unsigned short*)g_Wih1;
        for (int i = 0; i < 204; ++i) {
            float v = fabsf(bf2f(p[i]));
            if (!(v < 0.2f)) is16 = false;
        }
    }

    // ---- LDS staging
    for (int i = tid; i < 204 * PITCH; i += 256) {
        int r = i / PITCH, k = i - r * PITCH;
        smem[OFF_W1 + i] = (k < H) ? wget(g_Whh1, r * H + k, is16) : 0.f;
    }
    for (int i = tid; i < 153 * PITCH; i += 256) {
        int r = i / PITCH, k = i - r * PITCH;
        smem[OFF_W3 + i] = (k < H) ? wget(g_Wih3, (H + r) * H + k, is16) : 0.f;
    }
    __syncthreads();

    const int kbR = 13 * wid;                                   // register k-slice
    const int kbL = (wid == 0) ? 0 : (wid == 1) ? 12 : (wid == 2) ? 28 : 40;
    const int nbL = (wid == 1) ? 4 : 3;                         // float4 blocks in LDS slice

#define WC(srcp, row, kk) (((kbR + (kk)) < H) ? wget(srcp, (row) * H + kbR + (kk), is16) : 0.f)
#define DECL13(p) float p##_0,p##_1,p##_2,p##_3,p##_4,p##_5,p##_6,p##_7,p##_8,p##_9,p##_10,p##_11,p##_12;
#define LOAD13(p, srcp, row) \
    p##_0 = WC(srcp, row, 0);  p##_1 = WC(srcp, row, 1);  p##_2 = WC(srcp, row, 2); \
    p##_3 = WC(srcp, row, 3);  p##_4 = WC(srcp, row, 4);  p##_5 = WC(srcp, row, 5); \
    p##_6 = WC(srcp, row, 6);  p##_7 = WC(srcp, row, 7);  p##_8 = WC(srcp, row, 8); \
    p##_9 = WC(srcp, row, 9);  p##_10 = WC(srcp, row, 10); p##_11 = WC(srcp, row, 11); \
    p##_12 = WC(srcp, row, 12);

    DECL13(wih2g0) DECL13(wih2g1) DECL13(wih2g2) DECL13(wih2g3)
    DECL13(whh2g0) DECL13(whh2g1) DECL13(whh2g2) DECL13(whh2g3)
    DECL13(whh3g0) DECL13(whh3g1) DECL13(whh3g2) DECL13(whh3g3)
    DECL13(wih3i)
    LOAD13(wih2g0, g_Wih2, 0 * H + jeff) LOAD13(wih2g1, g_Wih2, 1 * H + jeff)
    LOAD13(wih2g2, g_Wih2, 2 * H + jeff) LOAD13(wih2g3, g_Wih2, 3 * H + jeff)
    LOAD13(whh2g0, g_Whh2, 0 * H + jeff) LOAD13(whh2g1, g_Whh2, 1 * H + jeff)
    LOAD13(whh2g2, g_Whh2, 2 * H + jeff) LOAD13(whh2g3, g_Whh2, 3 * H + jeff)
    LOAD13(whh3g0, g_Whh3, 0 * H + jeff) LOAD13(whh3g1, g_Whh3, 1 * H + jeff)
    LOAD13(whh3g2, g_Whh3, 2 * H + jeff) LOAD13(whh3g3, g_Whh3, 3 * H + jeff)
    LOAD13(wih3i,  g_Wih3, 0 * H + jeff)

    const float b1_0 = wget(g_bih1, 0*H+jeff, is16) + wget(g_bhh1, 0*H+jeff, is16);
    const float b1_1 = wget(g_bih1, 1*H+jeff, is16) + wget(g_bhh1, 1*H+jeff, is16);
    const float b1_2 = wget(g_bih1, 2*H+jeff, is16) + wget(g_bhh1, 2*H+jeff, is16);
    const float b1_3 = wget(g_bih1, 3*H+jeff, is16) + wget(g_bhh1, 3*H+jeff, is16);
    const float b2_0 = wget(g_bih2, 0*H+jeff, is16) + wget(g_bhh2, 0*H+jeff, is16);
    const float b2_1 = wget(g_bih2, 1*H+jeff, is16) + wget(g_bhh2, 1*H+jeff, is16);
    const float b2_2 = wget(g_bih2, 2*H+jeff, is16) + wget(g_bhh2, 2*H+jeff, is16);
    const float b2_3 = wget(g_bih2, 3*H+jeff, is16) + wget(g_bhh2, 3*H+jeff, is16);
    const float b3_0 = wget(g_bih3, 0*H+jeff, is16) + wget(g_bhh3, 0*H+jeff, is16);
    const float b3_1 = wget(g_bih3, 1*H+jeff, is16) + wget(g_bhh3, 1*H+jeff, is16);
    const float b3_2 = wget(g_bih3, 2*H+jeff, is16) + wget(g_bhh3, 2*H+jeff, is16);
    const float b3_3 = wget(g_bih3, 3*H+jeff, is16) + wget(g_bhh3, 3*H+jeff, is16);
    const float wi1_0 = wget(g_Wih1, 0*H+jeff, is16);
    const float wi1_1 = wget(g_Wih1, 1*H+jeff, is16);
    const float wi1_2 = wget(g_Wih1, 2*H+jeff, is16);
    const float wi1_3 = wget(g_Wih1, 3*H+jeff, is16);
    const float wlinr = (lane < H) ? wget(g_Wlin, lane, is16) : 0.f;
    const float blinr = wget(g_blin, 0, is16);

    const float4* A1g0 = (const float4*)(smem + OFF_W1 + (0*H + jeff) * PITCH + kbL);
    const float4* A1g1 = (const float4*)(smem + OFF_W1 + (1*H + jeff) * PITCH + kbL);
    const float4* A1g2 = (const float4*)(smem + OFF_W1 + (2*H + jeff) * PITCH + kbL);
    const float4* A1g3 = (const float4*)(smem + OFF_W1 + (3*H + jeff) * PITCH + kbL);
    const float4* A3f  = (const float4*)(smem + OFF_W3 + (      jeff) * PITCH + kbL);
    const float4* A3g  = (const float4*)(smem + OFF_W3 + (H   + jeff) * PITCH + kbL);
    const float4* A3o  = (const float4*)(smem + OFF_W3 + (2*H + jeff) * PITCH + kbL);
    float4* ebufP = (float4*)(smem + OFF_P);
    float*  hbuf  = smem + OFF_H;

    float h1_0=0.f,h1_1=0.f,h2_0=0.f,h2_1=0.f,h3_0=0.f,h3_1=0.f;
    float c1my=0.f,c2my=0.f,c3my=0.f;      // live in waves 0/2 only
    float xf0=0.f,xf1=0.f;                 // wave 3 only

    const unsigned short* in16 = (const unsigned short*)g_in;
    const float*          in32 = (const float*)g_in;
    unsigned short* o16w0 = (unsigned short*)g_out + (size_t)(eb+0)*T_TOT;
    unsigned short* o16w1 = (unsigned short*)g_out + (size_t)(eb+1)*T_TOT;
    float* o32w0 = (float*)g_out + (size_t)(eb+0)*T_TOT;
    float* o32w1 = (float*)g_out + (size_t)(eb+1)*T_TOT;

#define P2(kk) { \
    float s0_ = rl(h1_0, kbR+(kk)), s1_ = rl(h1_1, kbR+(kk)); \
    float r0_ = rl(h2_0, kbR+(kk)), r1_ = rl(h2_1, kbR+(kk)); \
    a0_0=fmaf(wih2g0_##kk,s0_,a0_0); a0_1=fmaf(wih2g0_##kk,s1_,a0_1); \
    a1_0=fmaf(wih2g1_##kk,s0_,a1_0); a1_1=fmaf(wih2g1_##kk,s1_,a1_1); \
    a2_0=fmaf(wih2g2_##kk,s0_,a2_0); a2_1=fmaf(wih2g2_##kk,s1_,a2_1); \
    a3_0=fmaf(wih2g3_##kk,s0_,a3_0); a3_1=fmaf(wih2g3_##kk,s1_,a3_1); \
    a0_0=fmaf(whh2g0_##kk,r0_,a0_0); a0_1=fmaf(whh2g0_##kk,r1_,a0_1); \
    a1_0=fmaf(whh2g1_##kk,r0_,a1_0); a1_1=fmaf(whh2g1_##kk,r1_,a1_1); \
    a2_0=fmaf(whh2g2_##kk,r0_,a2_0); a2_1=fmaf(whh2g2_##kk,r1_,a2_1); \
    a3_0=fmaf(whh2g3_##kk,r0_,a3_0); a3_1=fmaf(whh2g3_##kk,r1_,a3_1); }

#define P3(kk) { \
    float s0_ = rl(h2_0, kbR+(kk)), s1_ = rl(h2_1, kbR+(kk)); \
    float r0_ = rl(h3_0, kbR+(kk)), r1_ = rl(h3_1, kbR+(kk)); \
    a0_0=fmaf(wih3i_##kk,s0_,a0_0);  a0_1=fmaf(wih3i_##kk,s1_,a0_1); \
    a0_0=fmaf(whh3g0_##kk,r0_,a0_0); a0_1=fmaf(whh3g0_##kk,r1_,a0_1); \
    a1_0=fmaf(whh3g1_##kk,r0_,a1_0); a1_1=fmaf(whh3g1_##kk,r1_,a1_1); \
    a2_0=fmaf(whh3g2_##kk,r0_,a2_0); a2_1=fmaf(whh3g2_##kk,r1_,a2_1); \
    a3_0=fmaf(whh3g3_##kk,r0_,a3_0); a3_1=fmaf(whh3g3_##kk,r1_,a3_1); }

    // exchange partials; waves 0/2 reduce+UPD for elem 0/1; h rebroadcast via LDS
#define EXCHL(hv0, hv1, cmy) { \
    if (lane < H) { \
        ebufP[(0*4 + wid)*PITCH + lane] = make_float4(a0_0, a1_0, a2_0, a3_0); \
        ebufP[(1*4 + wid)*PITCH + lane] = make_float4(a0_1, a1_1, a2_1, a3_1); \
    } \
    __syncthreads(); \
    if ((wid & 1) == 0) { \
        const float4* pb_ = ebufP + (wid >> 1) * 4 * PITCH; \
        float4 q_ = pb_[0*PITCH + jeff]; \
        float4 t_ = pb_[1*PITCH + jeff]; q_.x+=t_.x; q_.y+=t_.y; q_.z+=t_.z; q_.w+=t_.w; \
        t_ = pb_[2*PITCH + jeff]; q_.x+=t_.x; q_.y+=t_.y; q_.z+=t_.z; q_.w+=t_.w; \
        t_ = pb_[3*PITCH + jeff]; q_.x+=t_.x; q_.y+=t_.y; q_.z+=t_.z; q_.w+=t_.w; \
        float ig_ = sigm(q_.x), fg_ = sigm(q_.y), gg_ = tanh_f(q_.z), og_ = sigm(q_.w); \
        cmy = fg_ * cmy + ig_ * gg_; \
        float hn_ = og_ * tanh_f(cmy); \
        if (lane < H) hbuf[(wid >> 1) * PITCH + lane] = hn_; \
    } \
    __syncthreads(); \
    hv0 = hbuf[0*PITCH + jeff]; \
    hv1 = hbuf[1*PITCH + jeff]; }

#pragma clang loop unroll(disable)
    for (int t = 0; t < T_TOT; ++t) {
        float a0_0,a1_0,a2_0,a3_0,a0_1,a1_1,a2_1,a3_1;

        // ---------------- layer 1 ----------------
        if (wid == 3) {
            float x0, x1;
            if (t < T_IN) {
                if (is16) {
                    x0 = bf2f(in16[(size_t)(eb+0)*T_IN + t]);
                    x1 = bf2f(in16[(size_t)(eb+1)*T_IN + t]);
                } else {
                    x0 = in32[(size_t)(eb+0)*T_IN + t];
                    x1 = in32[(size_t)(eb+1)*T_IN + t];
                }
            } else { x0 = xf0; x1 = xf1; }
            a0_0 = fmaf(wi1_0, x0, b1_0); a0_1 = fmaf(wi1_0, x1, b1_0);
            a1_0 = fmaf(wi1_1, x0, b1_1); a1_1 = fmaf(wi1_1, x1, b1_1);
            a2_0 = fmaf(wi1_2, x0, b1_2); a2_1 = fmaf(wi1_2, x1, b1_2);
            a3_0 = fmaf(wi1_3, x0, b1_3); a3_1 = fmaf(wi1_3, x1, b1_3);
        } else {
            a0_0=a1_0=a2_0=a3_0=a0_1=a1_1=a2_1=a3_1=0.f;
        }
        for (int b = 0; b < nbL; ++b) {
            float4 u0 = A1g0[b], u1 = A1g1[b], u2 = A1g2[b], u3 = A1g3[b];
#pragma unroll
            for (int i = 0; i < 4; ++i) {
                int k = kbL + 4*b + i;
                float s0 = rl(h1_0, k), s1 = rl(h1_1, k);
                a0_0 = fmaf(f4e(u0,i), s0, a0_0); a0_1 = fmaf(f4e(u0,i), s1, a0_1);
                a1_0 = fmaf(f4e(u1,i), s0, a1_0); a1_1 = fmaf(f4e(u1,i), s1, a1_1);
                a2_0 = fmaf(f4e(u2,i), s0, a2_0); a2_1 = fmaf(f4e(u2,i), s1, a2_1);
                a3_0 = fmaf(f4e(u3,i), s0, a3_0); a3_1 = fmaf(f4e(u3,i), s1, a3_1);
            }
        }
        EXCHL(h1_0, h1_1, c1my)

        // ---------------- layer 2 ----------------
        if (wid == 3) {
            a0_0=a0_1=b2_0; a1_0=a1_1=b2_1; a2_0=a2_1=b2_2; a3_0=a3_1=b2_3;
        } else {
            a0_0=a1_0=a2_0=a3_0=a0_1=a1_1=a2_1=a3_1=0.f;
        }
        L13(P2)
        EXCHL(h2_0, h2_1, c2my)

        // ---------------- layer 3 ----------------
        if (wid == 3) {
            a0_0=a0_1=b3_0; a1_0=a1_1=b3_1; a2_0=a2_1=b3_2; a3_0=a3_1=b3_3;
        } else {
            a0_0=a1_0=a2_0=a3_0=a0_1=a1_1=a2_1=a3_1=0.f;
        }
        for (int b = 0; b < nbL; ++b) {
            float4 uf = A3f[b], ug = A3g[b], uo = A3o[b];
#pragma unroll
            for (int i = 0; i < 4; ++i) {
                int k = kbL + 4*b + i;
                float s0 = rl(h2_0, k), s1 = rl(h2_1, k);
                a1_0 = fmaf(f4e(uf,i), s0, a1_0); a1_1 = fmaf(f4e(uf,i), s1, a1_1);
                a2_0 = fmaf(f4e(ug,i), s0, a2_0); a2_1 = fmaf(f4e(ug,i), s1, a2_1);
                a3_0 = fmaf(f4e(uo,i), s0, a3_0); a3_1 = fmaf(f4e(uo,i), s1, a3_1);
            }
        }
        L13(P3)
        EXCHL(h3_0, h3_1, c3my)

        // ---------------- head: wave 3 only ----------------
        if (wid == 3) {
            float s0 = wlinr * h3_0; RED(s0) float ov0 = s0 + blinr;
            float s1 = wlinr * h3_1; RED(s1) float ov1 = s1 + blinr;
            xf0 = ov0; xf1 = ov1;
            if (lane == 0) {
                if (is16) { o16w0[t] = f2bf(ov0); o16w1[t] = f2bf(ov1); }
                else      { o32w0[t] = ov0;       o32w1[t] = ov1; }
            }
        }
    }
}

extern "C" void kernel_launch(void* const* d_in, const int* in_sizes, int n_in,
                              void* d_out, int out_size, void* d_ws, size_t ws_size,
                              hipStream_t stream) {
    (void)in_sizes; (void)n_in; (void)d_ws; (void)ws_size; (void)out_size;
    size_t shmem = LDSFL * sizeof(float);   // 81,328 B -> 2 blocks/CU
    hipFuncSetAttribute((const void*)lstm3_kernel,
                        hipFuncAttributeMaxDynamicSharedMemorySize, (int)shmem);
    lstm3_kernel<<<dim3(512), dim3(256), shmem, stream>>>(
        d_in[0],  d_in[1],  d_in[2],  d_in[3],  d_in[4],
        d_in[5],  d_in[6],  d_in[7],  d_in[8],
        d_in[9],  d_in[10], d_in[11], d_in[12],
        d_in[13], d_in[14], d_out);
}